// Round 2
// baseline (42.038 us; speedup 1.0000x reference)
//
#include <hip/hip_runtime.h>

// Problem constants (from reference):
//   codes:     [4096, 1376, 2] int32
//   codebooks: [2, 256, 1, 8]  float32  (16 KB total)
//   scales:    [4096, 1, 1, 1] float32
//   out:       [4096, 11008]   float32  = 180.4 MB
#define NOG 4096
#define NIG 1376
#define IGS 8

__global__ __launch_bounds__(256)
void aqlm_dequant_kernel(const int2* __restrict__ codes,     // [NOG*NIG] pairs
                         const float4* __restrict__ codebooks, // 1024 float4 (16 KB)
                         const float* __restrict__ scales,    // [NOG]
                         float4* __restrict__ out)            // [NOG*NIG*2]
{
    // Stage both codebooks in LDS: 2 books * 256 entries * 8 floats = 4096 floats
    // = 1024 float4 = 16 KB. Layout: book0 entries at [e*2, e*2+1], book1 at
    // [512 + e*2, 512 + e*2 + 1].
    __shared__ float4 lds_cb[1024];
    const int tid = threadIdx.x;
#pragma unroll
    for (int i = 0; i < 4; ++i)
        lds_cb[tid + i * 256] = codebooks[tid + i * 256];
    __syncthreads();

    const int gid = blockIdx.x * 256 + tid;     // one (og, ig) pair per thread
    const int og  = gid / NIG;
    // (no need for ig itself; flat layout matches: out row og, in-group ig)

    const int2 c  = codes[gid];                 // coalesced 8 B load
    const float s = scales[og];                 // broadcast within row, L1-cached

    const float4 a0 = lds_cb[c.x * 2];
    const float4 a1 = lds_cb[c.x * 2 + 1];
    const float4 b0 = lds_cb[512 + c.y * 2];
    const float4 b1 = lds_cb[512 + c.y * 2 + 1];

    float4 w0, w1;
    w0.x = (a0.x + b0.x) * s;
    w0.y = (a0.y + b0.y) * s;
    w0.z = (a0.z + b0.z) * s;
    w0.w = (a0.w + b0.w) * s;
    w1.x = (a1.x + b1.x) * s;
    w1.y = (a1.y + b1.y) * s;
    w1.z = (a1.z + b1.z) * s;
    w1.w = (a1.w + b1.w) * s;

    out[gid * 2]     = w0;   // wave writes contiguous 2 KB (2 x dwordx4/lane)
    out[gid * 2 + 1] = w1;
}

extern "C" void kernel_launch(void* const* d_in, const int* in_sizes, int n_in,
                              void* d_out, int out_size, void* d_ws, size_t ws_size,
                              hipStream_t stream) {
    const int2*   codes     = (const int2*)d_in[0];
    const float4* codebooks = (const float4*)d_in[1];
    const float*  scales    = (const float*)d_in[2];
    float4*       out       = (float4*)d_out;

    const int total_pairs = NOG * NIG;          // 5,636,096
    const int blocks = total_pairs / 256;       // 22016, exact (no tail)
    aqlm_dequant_kernel<<<blocks, 256, 0, stream>>>(codes, codebooks, scales, out);
}